// Round 1
// baseline (1670.343 us; speedup 1.0000x reference)
//
#include <hip/hip_runtime.h>
#include <math.h>

#define MDIM   4096
#define NSTEPS 199
#define NBLK   256     // one block per CU
#define NTHR   1024    // 16 waves; wave w owns row bid*16+w
#define B1C    0.9f
#define B2C    0.999f
#define EPSC   1e-8f

typedef unsigned long long u64;

// Tagged u element: high 32 bits = step tag, low 32 bits = float value.
// One 8-byte relaxed agent-scope atomic carries BOTH data and readiness,
// so readiness detection and data transfer share a single global round trip.
__device__ __forceinline__ u64 pack_uv(float v, unsigned t) {
    return ((u64)t << 32) | (u64)__float_as_uint(v);
}
__device__ __forceinline__ float    unpack_v(u64 p) { return __uint_as_float((unsigned)p); }
__device__ __forceinline__ unsigned unpack_t(u64 p) { return (unsigned)(p >> 32); }

// ---------------------------------------------------------------------------
// Prep: Qs[i][j] = 0.5*(va[i][j] + va[j][i]), LDS-tiled transpose (validated).
// ---------------------------------------------------------------------------
__global__ void prep_qs(const float* __restrict__ va, float* __restrict__ Qs) {
    __shared__ float tile[32][33];
    const int j0 = blockIdx.x * 32;
    const int i0 = blockIdx.y * 32;
    const int tx = threadIdx.x, ty = threadIdx.y;

    for (int k = 0; k < 32; k += 8)
        tile[ty + k][tx] = va[(size_t)(j0 + ty + k) * MDIM + i0 + tx];
    __syncthreads();
    for (int k = 0; k < 32; k += 8) {
        int i = i0 + ty + k;
        float a = va[(size_t)i * MDIM + j0 + tx];
        float b = tile[tx][ty + k];          // va[j][i]
        Qs[(size_t)i * MDIM + j0 + tx] = 0.5f * (a + b);
    }
}

// ---------------------------------------------------------------------------
// Init: u0[i] = (tag=0, value=1-mean[i]). u1 needs no init: its stale tags
// from a previous launch are 1..199 but each location is overwritten with
// tag 1 before any spinner can wait on tags 3,5,... (monotone history).
// ---------------------------------------------------------------------------
__global__ void init_state(const float* __restrict__ mean, u64* __restrict__ u0) {
    int i = blockIdx.x * blockDim.x + threadIdx.x;
    if (i < MDIM) u0[i] = pack_uv(1.0f - mean[i], 0u);
}

// ---------------------------------------------------------------------------
// Persistent cooperative kernel, fp32 end-to-end.
// Wave w of block b owns row r=16b+w; its Q row lives in 64 regs/lane
// (unified-file AGPRs), loaded once. Per step: spin-load tagged u (the spin
// IS the grid barrier — all tags==t-1 implies every block finished and READ
// step t-1, so double-buffer overwrite is safe), stage to LDS su[t&1]
// (2-buffer -> ONE __syncthreads per step), reg-dot, butterfly reduce,
// Adam in registers, publish tagged u[row]. No flag array, no poll loop.
// ---------------------------------------------------------------------------
__global__ __launch_bounds__(NTHR) void adam_persist(
        const float* __restrict__ Qs,
        u64* u0, u64* u1,
        const float* __restrict__ mean,
        float* __restrict__ w_out) {
    __shared__ float su[2][MDIM];

    const int tid  = threadIdx.x;
    const int bid  = blockIdx.x;
    const int wave = tid >> 6;
    const int lane = tid & 63;
    const int row  = bid * 16 + wave;

    // ---- one-time: Q row -> registers (64 regs/lane) ----
    float4 qreg[16];
    const float4* qrow4 = (const float4*)(Qs + (size_t)row * MDIM);
#pragma unroll
    for (int it = 0; it < 16; ++it) qreg[it] = qrow4[lane + 64 * it];

    float m = 0.0f, v = 0.0f, b1p = 1.0f, b2p = 1.0f, unew = 0.0f;

    const int i0 = tid;
    const int i1 = tid + NTHR;
    const int i2 = tid + 2 * NTHR;
    const int i3 = tid + 3 * NTHR;

    for (int t = 1; t <= NSTEPS; ++t) {
        u64* uin  = (t & 1) ? u0 : u1;   // t=1 reads u0 (tag 0)
        u64* uout = (t & 1) ? u1 : u0;
        const unsigned tg = (unsigned)(t - 1);
        const int b = t & 1;

        // ---- spin directly on tagged data: 4 strided coalesced 8B loads ----
        u64 q0, q1, q2, q3;
        int spin = 0;
        for (;;) {
            q0 = __hip_atomic_load(uin + i0, __ATOMIC_RELAXED, __HIP_MEMORY_SCOPE_AGENT);
            q1 = __hip_atomic_load(uin + i1, __ATOMIC_RELAXED, __HIP_MEMORY_SCOPE_AGENT);
            q2 = __hip_atomic_load(uin + i2, __ATOMIC_RELAXED, __HIP_MEMORY_SCOPE_AGENT);
            q3 = __hip_atomic_load(uin + i3, __ATOMIC_RELAXED, __HIP_MEMORY_SCOPE_AGENT);
            if ((unpack_t(q0) == tg) & (unpack_t(q1) == tg) &
                (unpack_t(q2) == tg) & (unpack_t(q3) == tg)) break;
            if (++spin > (1 << 18)) break;   // fail visibly, never hang
        }
        su[b][i0] = unpack_v(q0);
        su[b][i1] = unpack_v(q1);
        su[b][i2] = unpack_v(q2);
        su[b][i3] = unpack_v(q3);
        // Single barrier/step: writes to su[b] at t cannot race reads of
        // su[b] at t-2 because both sides are separated by t-1's barrier.
        __syncthreads();

        // ---- row dot from registers ----
        float acc = 0.0f;
        const float4* sbuf4 = (const float4*)su[b];
#pragma unroll
        for (int it = 0; it < 16; ++it) {
            float4 q = qreg[it];
            float4 u = sbuf4[lane + 64 * it];
            acc += q.x * u.x + q.y * u.y + q.z * u.z + q.w * u.w;
        }
#pragma unroll
        for (int off = 32; off > 0; off >>= 1) acc += __shfl_xor(acc, off);
        const float g = acc;

        // ---- Adam update (state in registers, replicated across lanes) ----
        b1p *= B1C;
        b2p *= B2C;
        m = B1C * m + (1.0f - B1C) * g;
        v = B2C * v + (1.0f - B2C) * g * g;
        const float denom = sqrtf(v) / sqrtf(1.0f - b2p) + EPSC;
        unew = su[b][row] - (0.1f / (1.0f - b1p)) * m / denom;

        // ---- publish tagged result; tag+value travel in one 8B atom ----
        if (lane == 0)
            __hip_atomic_store(uout + row, pack_uv(unew, (unsigned)t),
                               __ATOMIC_RELAXED, __HIP_MEMORY_SCOPE_AGENT);
    }

    if (lane == 0) w_out[row] = unew + mean[row];
}

extern "C" void kernel_launch(void* const* d_in, const int* in_sizes, int n_in,
                              void* d_out, int out_size, void* d_ws, size_t ws_size,
                              hipStream_t stream) {
    const float* mean = (const float*)d_in[0];   // (4096,)
    const float* va   = (const float*)d_in[1];   // (4096,4096)
    float* w_out = (float*)d_out;                // (4096,)

    float* ws = (float*)d_ws;
    float* Qs = ws;                              // 64 MB
    u64*   u0 = (u64*)(ws + (size_t)MDIM * MDIM); // 32 KB tagged
    u64*   u1 = u0 + MDIM;                        // 32 KB tagged

    prep_qs<<<dim3(MDIM / 32, MDIM / 32), dim3(32, 8), 0, stream>>>(va, Qs);
    init_state<<<(MDIM + 255) / 256, 256, 0, stream>>>(mean, u0);

    void* args[] = { (void*)&Qs, (void*)&u0, (void*)&u1,
                     (void*)&mean, (void*)&w_out };
    hipLaunchCooperativeKernel((const void*)adam_persist,
                               dim3(NBLK), dim3(NTHR), args, 0, stream);
}